// Round 2
// baseline (2829.451 us; speedup 1.0000x reference)
//
#include <hip/hip_runtime.h>
#include <hip/hip_bf16.h>
#include <stdint.h>

#define SEQ 4096
#define DIM 4096
#define NH 32
#define NKV 8
#define HD 128
// GEMM: M=16384 (4*4096), N=6144 (q 4096 | k 1024 | v 1024), K=4096. All fp32 I/O.

typedef __bf16 bf16x8 __attribute__((ext_vector_type(8)));
typedef float f32x4 __attribute__((ext_vector_type(4)));

__device__ __forceinline__ void gl_lds16(const float* g, void* l) {
    __builtin_amdgcn_global_load_lds(
        (const __attribute__((address_space(1))) void*)g,
        (__attribute__((address_space(3))) void*)l, 16, 0, 0);
}

// 128x128 block tile, 4 waves (2x2), each wave 64x64 via 4x4 x mfma_f32_16x16x32_bf16.
// fp32 tiles staged to LDS (direct DMA), converted to bf16 in registers post-ds_read.
__global__ __launch_bounds__(256, 2)
void qkv_rope_kernel(const float* __restrict__ x,
                     const float* __restrict__ wq,
                     const float* __restrict__ wk,
                     const float* __restrict__ wv,
                     const float* __restrict__ cosT,
                     const float* __restrict__ sinT,
                     float* __restrict__ out) {
    // [128 rows][32 k] fp32 = 16 KB per tile. Row = 8 chunks of 16B;
    // phys_chunk = logical_chunk ^ (row&7) -> conflict-free ds_read_b128.
    __shared__ __align__(16) float lA[128 * 32];
    __shared__ __align__(16) float lB[128 * 32];

    const int t = threadIdx.x;
    const int lane = t & 63;
    const int w = t >> 6;
    const int bn = blockIdx.x;   // 0..47 fastest -> W stays L3-resident
    const int bm = blockIdx.y;   // 0..127

    const float* W;
    int n_mat;
    if (bn < 32)      { W = wq; n_mat = bn << 7; }
    else if (bn < 40) { W = wk; n_mat = (bn - 32) << 7; }
    else              { W = wv; n_mat = (bn - 40) << 7; }

    const int m0 = bm << 7;

    // staging: tile elem (16B chunk) gi = i*256 + t; row = gi>>3; phys chunk = t&7;
    // logical chunk = phys ^ (row&7); global col (floats) = logical*4
    const float* gA[4]; const float* gB[4];
#pragma unroll
    for (int i = 0; i < 4; i++) {
        const int row = i * 32 + (t >> 3);
        const int lc = (t & 7) ^ (row & 7);
        gA[i] = x + (size_t)(m0 + row) * DIM + lc * 4;
        gB[i] = W + (size_t)(n_mat + row) * DIM + lc * 4;
    }
    char* lAc = (char*)lA;
    char* lBc = (char*)lB;

    const int wm = (w & 1) << 6;   // wave m offset: 0/64
    const int wn = (w >> 1) << 6;  // wave n offset: 0/64
    const int fr = lane & 15;      // fragment row
    const int q4 = lane >> 4;      // k-quad: frag holds k = q4*8 .. q4*8+7

    // two 16B LDS reads per fragment (logical chunks 2q4, 2q4+1), swizzle folded in
    int offA0[4], offA1[4], offB0[4], offB1[4];
#pragma unroll
    for (int i = 0; i < 4; i++) {
        const int ra = wm + i * 16 + fr;
        offA0[i] = ra * 128 + (((2 * q4)     ^ (ra & 7)) * 16);
        offA1[i] = ra * 128 + (((2 * q4 + 1) ^ (ra & 7)) * 16);
        const int rb = wn + i * 16 + fr;
        offB0[i] = rb * 128 + (((2 * q4)     ^ (rb & 7)) * 16);
        offB1[i] = rb * 128 + (((2 * q4 + 1) ^ (rb & 7)) * 16);
    }

    f32x4 acc[4][4];
#pragma unroll
    for (int i = 0; i < 4; i++)
#pragma unroll
        for (int j = 0; j < 4; j++)
            acc[i][j] = (f32x4){0.f, 0.f, 0.f, 0.f};

    for (int k0 = 0; k0 < DIM; k0 += 32) {
#pragma unroll
        for (int i = 0; i < 4; i++) {
            gl_lds16(gA[i], lAc + i * 4096 + w * 1024);
            gl_lds16(gB[i], lBc + i * 4096 + w * 1024);
            gA[i] += 32; gB[i] += 32;
        }
        __syncthreads();   // drains vmcnt -> tiles visible

        bf16x8 af[4], bfr[4];
#pragma unroll
        for (int i = 0; i < 4; i++) {
            const f32x4 a0 = *(const f32x4*)(lAc + offA0[i]);
            const f32x4 a1 = *(const f32x4*)(lAc + offA1[i]);
            bf16x8 v;
#pragma unroll
            for (int e = 0; e < 4; e++) { v[e] = (__bf16)a0[e]; v[4 + e] = (__bf16)a1[e]; }
            af[i] = v;
        }
#pragma unroll
        for (int i = 0; i < 4; i++) {
            const f32x4 b0 = *(const f32x4*)(lBc + offB0[i]);
            const f32x4 b1 = *(const f32x4*)(lBc + offB1[i]);
            bf16x8 v;
#pragma unroll
            for (int e = 0; e < 4; e++) { v[e] = (__bf16)b0[e]; v[4 + e] = (__bf16)b1[e]; }
            bfr[i] = v;
        }
#pragma unroll
        for (int i = 0; i < 4; i++)
#pragma unroll
            for (int j = 0; j < 4; j++)
                acc[i][j] = __builtin_amdgcn_mfma_f32_16x16x32_bf16(af[i], bfr[j], acc[i][j], 0, 0, 0);
        __syncthreads();   // protect LDS before next staging
    }

    // ---- epilogue: RoPE (q,k) + transposed (b,h,s,d) store, fp32 ----
    const size_t QSZ = (size_t)4 * NH * SEQ * HD;
    const size_t KSZ = (size_t)4 * NKV * SEQ * HD;
    size_t region, bstr;
    bool do_rope;
    if (bn < 32)      { region = 0;         bstr = (size_t)NH  * SEQ * HD; do_rope = true; }
    else if (bn < 40) { region = QSZ;       bstr = (size_t)NKV * SEQ * HD; do_rope = true; }
    else              { region = QSZ + KSZ; bstr = (size_t)NKV * SEQ * HD; do_rope = false; }

    const int col_l = lane & 15;
#pragma unroll
    for (int j = 0; j < 4; j++) {
        const int n_local = n_mat + wn + j * 16 + col_l;
        const int h = n_local >> 7;
        const int d = n_local & 127;
        const int fidx = d >> 1;
        const size_t base_j = region + (size_t)h * (SEQ * HD) + d;
#pragma unroll
        for (int i = 0; i < 4; i++) {
            const int mrow = m0 + wm + i * 16 + q4 * 4;
#pragma unroll
            for (int r = 0; r < 4; r++) {
                const int m = mrow + r;
                const int b = m >> 12;          // SEQ = 4096
                const int s = m & (SEQ - 1);
                float v = acc[i][j][r];
                if (do_rope) {
                    const float cv = cosT[s * 64 + fidx];
                    const float sv = sinT[s * 64 + fidx];
                    const float other = __shfl_xor(v, 1, 64);
                    // even d: t1*c - t2*s ; odd d: t1*s + t2*c
                    v = (d & 1) ? fmaf(v, cv, other * sv) : fmaf(v, cv, -other * sv);
                }
                out[base_j + (size_t)b * bstr + (size_t)s * HD] = v;
            }
        }
    }
}

extern "C" void kernel_launch(void* const* d_in, const int* in_sizes, int n_in,
                              void* d_out, int out_size, void* d_ws, size_t ws_size,
                              hipStream_t stream) {
    const float* x    = (const float*)d_in[0];
    const float* wq   = (const float*)d_in[1];
    const float* wk   = (const float*)d_in[2];
    const float* wv   = (const float*)d_in[3];
    const float* cosT = (const float*)d_in[4];
    const float* sinT = (const float*)d_in[5];
    float* out = (float*)d_out;

    dim3 grid(48, 128);   // bn fastest (W L3-resident), bm slabs
    dim3 block(256);
    qkv_rope_kernel<<<grid, block, 0, stream>>>(x, wq, wk, wv, cosT, sinT, out);
}